// Round 2
// baseline (2594.245 us; speedup 1.0000x reference)
//
#include <hip/hip_runtime.h>

using f32x4 = __attribute__((ext_vector_type(4))) float;
using s16x8 = __attribute__((ext_vector_type(8))) short;
using u32x2 = __attribute__((ext_vector_type(2))) unsigned int;

#define NROWS 100000

__device__ __forceinline__ unsigned short f2bf(float f) {
    unsigned int u = __float_as_uint(f);
    u = (u + 0x7fffu + ((u >> 16) & 1u)) >> 16;
    return (unsigned short)u;
}

__device__ __forceinline__ float sigm(float x) { return 1.0f / (1.0f + __expf(-x)); }

#define MFMA(a, b, c) __builtin_amdgcn_mfma_f32_16x16x32_bf16((a), (b), (c), 0, 0, 0)

// ---------------- weight pack (single launch for all 8) ----------------
// W (K x Nn row-major f32) -> Wt (Nn x K row-major bf16), scale folded. K pow2.
__device__ __forceinline__ void packseg(const float* __restrict__ W, unsigned short* __restrict__ dst,
                                        int i, int logK, int Nn, float scale) {
    int n = i >> logK, k = i & ((1 << logK) - 1);
    dst[i] = f2bf(W[(size_t)k * Nn + n] * scale);
}

__global__ void pack_w_all(const float* __restrict__ w10, const float* __restrict__ w11,
                           const float* __restrict__ w20, const float* __restrict__ w21,
                           const float* __restrict__ w30, const float* __restrict__ w31,
                           const float* __restrict__ wb0, const float* __restrict__ wb1,
                           unsigned short* __restrict__ out) {
    const float S16  = 0.0625f;               // 1/sqrt(256)
    const float S128 = 0.08838834764831845f;  // 1/sqrt(128)
    const float S512 = 0.04419417382415922f;  // 1/sqrt(512)
    int idx = blockIdx.x * blockDim.x + threadIdx.x;
    if (idx < 196608)        packseg(w10, out,          idx,          8, 768, S16);
    else if (idx < 229376)   packseg(w11, out + 196608, idx - 196608, 7, 256, S128);
    else if (idx < 622592)   packseg(w20, out + 229376, idx - 229376, 9, 768, S512);
    else if (idx < 688128)   packseg(w21, out + 622592, idx - 622592, 8, 256, S16);
    else if (idx < 819200)   packseg(w30, out + 688128, idx - 688128, 9, 256, S512);
    else if (idx < 851968)   packseg(w31, out + 819200, idx - 819200, 8, 128, S16);
    else if (idx < 917504)   packseg(wb0, out + 851968, idx - 851968, 8, 256, S16);
    else if (idx < 933888)   packseg(wb1, out + 917504, idx - 917504, 7, 128, S128);
}

// ---------------- feature pack ----------------
// features (N x 640 f32, vector interleaved 256+3j+d) ->
// Xs (N x 640 bf16, de-interleaved [s 256 | d0 128 | d1 128 | d2 128])
__global__ void pack_x(const float* __restrict__ F, unsigned short* __restrict__ Xs) {
    size_t total = (size_t)NROWS * 160;  // groups of 4 cols
    size_t stride = (size_t)gridDim.x * blockDim.x;
    for (size_t g = (size_t)blockIdx.x * blockDim.x + threadIdx.x; g < total; g += stride) {
        size_t n = g / 160;
        int c0 = (int)(g - n * 160) * 4;
        const float* row = F + n * 640;
        unsigned short o[4];
        if (c0 < 256) {
            f32x4 v = *(const f32x4*)(row + c0);
            #pragma unroll
            for (int q = 0; q < 4; ++q) o[q] = f2bf(v[q]);
        } else {
            int u = c0 - 256;
            int d = u >> 7, j = u & 127;
            int base = 256 + 3 * j + d;
            #pragma unroll
            for (int q = 0; q < 4; ++q) o[q] = f2bf(row[base + 3 * q]);
        }
        u32x2 pk;
        pk[0] = (unsigned int)o[0] | ((unsigned int)o[1] << 16);
        pk[1] = (unsigned int)o[2] | ((unsigned int)o[3] << 16);
        *(u32x2*)(Xs + n * 640 + c0) = pk;
    }
}

// ---------------- layer 1/2: irlin + gate (intra-wave gating) ----------------
// Xin: N x (K0+3K1) bf16 de-interleaved. Out: N x 1280 bf16 de-interleaved
// [silu 512 | d0 256 | d1 256 | d2 256]. In-place safe (sync before stores;
// 16 rows/block, row-exclusive).
// Wave w: silu tiles cols 64w..64w+63 (4 tiles, K=K0),
//         gate tiles cols 512+32w..+31 of H0 (2 tiles, K=K0),
//         vector j-tiles j=32w..32w+31 (2 tiles x 3 d, K=K1, shared B).
template<int K0, int K1>
__global__ __launch_bounds__(512, 4) void layer12_v2(
        const unsigned short* Xin,
        const unsigned short* __restrict__ W0t,
        const unsigned short* __restrict__ W1t,
        unsigned short* Out) {
    constexpr int CIN = K0 + 3 * K1;
    const int tid = threadIdx.x, wid = tid >> 6, lane = tid & 63;
    const int row0 = blockIdx.x * 16;
    const int lrow = lane & 15;
    const int lk = (lane >> 4) << 3;

    f32x4 accS[4], accG[2], accV[2][3];
    const f32x4 vz = {0.f, 0.f, 0.f, 0.f};
    #pragma unroll
    for (int i = 0; i < 4; ++i) accS[i] = vz;
    #pragma unroll
    for (int i = 0; i < 2; ++i) {
        accG[i] = vz;
        #pragma unroll
        for (int d = 0; d < 3; ++d) accV[i][d] = vz;
    }

    const unsigned short* xp = Xin + (size_t)(row0 + lrow) * CIN + lk;
    const unsigned short* bs = W0t + (size_t)(64 * wid + lrow) * K0 + lk;
    const unsigned short* bg = W0t + (size_t)(512 + 32 * wid + lrow) * K0 + lk;

    #pragma unroll
    for (int ks = 0; ks < K0 / 32; ++ks) {
        const int k = ks * 32;
        s16x8 a = *(const s16x8*)(xp + k);
        #pragma unroll
        for (int i = 0; i < 4; ++i) {
            s16x8 b = *(const s16x8*)(bs + (size_t)(16 * i) * K0 + k);
            accS[i] = MFMA(a, b, accS[i]);
        }
        #pragma unroll
        for (int i = 0; i < 2; ++i) {
            s16x8 b = *(const s16x8*)(bg + (size_t)(16 * i) * K0 + k);
            accG[i] = MFMA(a, b, accG[i]);
        }
    }

    const unsigned short* bv = W1t + (size_t)(32 * wid + lrow) * K1 + lk;
    #pragma unroll
    for (int ks = 0; ks < K1 / 32; ++ks) {
        const int k = ks * 32;
        s16x8 a0 = *(const s16x8*)(xp + K0 + k);
        s16x8 a1 = *(const s16x8*)(xp + K0 + K1 + k);
        s16x8 a2 = *(const s16x8*)(xp + K0 + 2 * K1 + k);
        #pragma unroll
        for (int i = 0; i < 2; ++i) {
            s16x8 b = *(const s16x8*)(bv + (size_t)(16 * i) * K1 + k);
            accV[i][0] = MFMA(a0, b, accV[i][0]);
            accV[i][1] = MFMA(a1, b, accV[i][1]);
            accV[i][2] = MFMA(a2, b, accV[i][2]);
        }
    }

    __syncthreads();  // all reads of Xin done (in-place safety for layer2)

    const int colg = lane & 15;
    const int rbase = (lane >> 4) * 4;
    #pragma unroll
    for (int r = 0; r < 4; ++r) {
        const size_t ro = (size_t)(row0 + rbase + r) * 1280;
        #pragma unroll
        for (int i = 0; i < 4; ++i) {
            float v = accS[i][r];
            Out[ro + 64 * wid + 16 * i + colg] = f2bf(v * sigm(v));
        }
        #pragma unroll
        for (int i = 0; i < 2; ++i) {
            float g = sigm(accG[i][r]);
            #pragma unroll
            for (int d = 0; d < 3; ++d) {
                Out[ro + 512 + 256 * d + 32 * wid + 16 * i + colg] = f2bf(accV[i][d][r] * g);
            }
        }
    }
}

// ---------------- layer 3 + bypass + stats ----------------
// G2: N x 1280 bf16. Xs: N x 640 bf16. OutF: N x 640 f32 (same bytes as G2 rows).
// Wave w: scalar tiles cols 32w..+31 (2 tiles), vector j-tile j=16w..+15 (x3 d).
__global__ __launch_bounds__(512, 4) void layer3_v2(
        const unsigned short* G2,
        const unsigned short* __restrict__ W0t,   // W30 (256 x 512)
        const unsigned short* __restrict__ W1t,   // W31 (128 x 256)
        const unsigned short* __restrict__ Xs,
        const unsigned short* __restrict__ Wb0,   // (256 x 256)
        const unsigned short* __restrict__ Wb1,   // (128 x 128)
        float* OutF, float* __restrict__ stats) {
    const int tid = threadIdx.x, wid = tid >> 6, lane = tid & 63;
    const int row0 = blockIdx.x * 16;
    const int lrow = lane & 15, lk = (lane >> 4) << 3;

    f32x4 accS[2], accV[3];
    const f32x4 vz = {0.f, 0.f, 0.f, 0.f};
    accS[0] = vz; accS[1] = vz; accV[0] = vz; accV[1] = vz; accV[2] = vz;

    const unsigned short* gp = G2 + (size_t)(row0 + lrow) * 1280 + lk;
    const unsigned short* xp = Xs + (size_t)(row0 + lrow) * 640 + lk;

    {   // scalar from G2 (K=512)
        const unsigned short* b0 = W0t + (size_t)(32 * wid + lrow) * 512 + lk;
        #pragma unroll
        for (int ks = 0; ks < 16; ++ks) {
            const int k = ks * 32;
            s16x8 a = *(const s16x8*)(gp + k);
            #pragma unroll
            for (int i = 0; i < 2; ++i) {
                s16x8 b = *(const s16x8*)(b0 + (size_t)(16 * i) * 512 + k);
                accS[i] = MFMA(a, b, accS[i]);
            }
        }
    }
    {   // scalar bypass from Xs (K=256)
        const unsigned short* c0 = Wb0 + (size_t)(32 * wid + lrow) * 256 + lk;
        #pragma unroll
        for (int ks = 0; ks < 8; ++ks) {
            const int k = ks * 32;
            s16x8 a = *(const s16x8*)(xp + k);
            #pragma unroll
            for (int i = 0; i < 2; ++i) {
                s16x8 b = *(const s16x8*)(c0 + (size_t)(16 * i) * 256 + k);
                accS[i] = MFMA(a, b, accS[i]);
            }
        }
    }
    {   // vector from G2 (K=256, shared B across d)
        const unsigned short* b1 = W1t + (size_t)(16 * wid + lrow) * 256 + lk;
        #pragma unroll
        for (int ks = 0; ks < 8; ++ks) {
            const int k = ks * 32;
            s16x8 b = *(const s16x8*)(b1 + k);
            #pragma unroll
            for (int d = 0; d < 3; ++d) {
                s16x8 a = *(const s16x8*)(gp + 512 + 256 * d + k);
                accV[d] = MFMA(a, b, accV[d]);
            }
        }
    }
    {   // vector bypass from Xs (K=128)
        const unsigned short* c1 = Wb1 + (size_t)(16 * wid + lrow) * 128 + lk;
        #pragma unroll
        for (int ks = 0; ks < 4; ++ks) {
            const int k = ks * 32;
            s16x8 b = *(const s16x8*)(c1 + k);
            #pragma unroll
            for (int d = 0; d < 3; ++d) {
                s16x8 a = *(const s16x8*)(xp + 256 + 128 * d + k);
                accV[d] = MFMA(a, b, accV[d]);
            }
        }
    }

    __syncthreads();  // all reads of G2 rows done before overwriting with f32

    const int colg = lane & 15, rbase = (lane >> 4) * 4;
    #pragma unroll
    for (int i = 0; i < 2; ++i) {
        const int col = 32 * wid + 16 * i + colg;
        float s0 = 0.f, s1 = 0.f;
        #pragma unroll
        for (int r = 0; r < 4; ++r) {
            float v = accS[i][r];
            OutF[(size_t)(row0 + rbase + r) * 640 + col] = v;
            s0 += v; s1 += v * v;
        }
        s0 += __shfl_xor(s0, 16); s0 += __shfl_xor(s0, 32);
        s1 += __shfl_xor(s1, 16); s1 += __shfl_xor(s1, 32);
        if (lane < 16) { atomicAdd(&stats[col], s0); atomicAdd(&stats[256 + col], s1); }
    }
    #pragma unroll
    for (int d = 0; d < 3; ++d) {
        const int j = 16 * wid + colg;
        float s1 = 0.f;
        #pragma unroll
        for (int r = 0; r < 4; ++r) {
            float v = accV[d][r];
            OutF[(size_t)(row0 + rbase + r) * 640 + 256 + 128 * d + j] = v;
            s1 += v * v;
        }
        s1 += __shfl_xor(s1, 16); s1 += __shfl_xor(s1, 32);
        if (lane < 16) atomicAdd(&stats[512 + 128 * d + j], s1);
    }
}

// ---------------- batchnorm ----------------
__global__ void bn_finalize(const float* __restrict__ stats, const float* __restrict__ bnw,
                            const float* __restrict__ bnb, float* __restrict__ params) {
    int c = threadIdx.x;
    const float invN = 1.0f / (float)NROWS;
    if (c < 256) {
        float mean = stats[c] * invN;
        float var = stats[256 + c] * invN - mean * mean;
        float sc = rsqrtf(var + 1e-5f) * bnw[c];
        params[c] = sc;
        params[256 + c] = bnb[c] - mean * sc;
    } else if (c < 384) {
        int j = c - 256;
        float sv = stats[512 + j] + stats[640 + j] + stats[768 + j];
        float vinv = rsqrtf(sv * (invN * (1.0f / 3.0f)) + 1e-5f) * bnw[256 + j];
        params[512 + j] = vinv;
    }
}

__global__ void bn_apply(const float* __restrict__ OutF, const float* __restrict__ params,
                         float* __restrict__ out) {
    size_t total = (size_t)NROWS * 640;
    size_t stride = (size_t)gridDim.x * blockDim.x * 4;
    for (size_t base = ((size_t)blockIdx.x * blockDim.x + threadIdx.x) * 4; base < total; base += stride) {
        size_t n = base / 640;
        int c0 = (int)(base - n * 640);
        const float* rowp = OutF + n * 640;
        f32x4 o;
        #pragma unroll
        for (int q = 0; q < 4; ++q) {
            int c = c0 + q;
            if (c < 256) {
                o[q] = rowp[c] * params[c] + params[256 + c];
            } else {
                int u = c - 256; int j = u / 3; int d = u - 3 * j;
                o[q] = rowp[256 + d * 128 + j] * params[512 + j];
            }
        }
        *(f32x4*)(out + base) = o;
    }
}

// ---------------- launch ----------------
extern "C" void kernel_launch(void* const* d_in, const int* in_sizes, int n_in,
                              void* d_out, int out_size, void* d_ws, size_t ws_size,
                              hipStream_t stream) {
    const float* features = (const float*)d_in[0];
    const float* l1w0 = (const float*)d_in[1];
    const float* l1w1 = (const float*)d_in[2];
    const float* l2w0 = (const float*)d_in[3];
    const float* l2w1 = (const float*)d_in[4];
    const float* l3w0 = (const float*)d_in[5];
    const float* l3w1 = (const float*)d_in[6];
    const float* bw0  = (const float*)d_in[7];
    const float* bw1  = (const float*)d_in[8];
    const float* bnw  = (const float*)d_in[9];
    const float* bnb  = (const float*)d_in[10];
    float* out = (float*)d_out;
    char* ws = (char*)d_ws;

    unsigned short* Wt = (unsigned short*)(ws + 0);  // 933888 elems, contiguous
    unsigned short* W10 = Wt + 0;
    unsigned short* W11 = Wt + 196608;
    unsigned short* W20 = Wt + 229376;
    unsigned short* W21 = Wt + 622592;
    unsigned short* W30 = Wt + 688128;
    unsigned short* W31 = Wt + 819200;
    unsigned short* WB0 = Wt + 851968;
    unsigned short* WB1 = Wt + 917504;
    float* stats  = (float*)(ws + 1900544);                 // 896 f32
    float* params = (float*)(ws + 1904128);                 // 640 f32
    unsigned short* Xs = (unsigned short*)(ws + 2097152);   // 100000x640 bf16
    unsigned short* G  = (unsigned short*)(ws + 130097152); // 100000x1280 bf16 (becomes OutF f32)
    float* Gf = (float*)G;

    hipMemsetAsync(stats, 0, 896 * sizeof(float), stream);

    pack_w_all<<<3648, 256, 0, stream>>>(l1w0, l1w1, l2w0, l2w1, l3w0, l3w1, bw0, bw1, Wt);
    pack_x<<<4096, 256, 0, stream>>>(features, Xs);

    layer12_v2<256, 128><<<6250, 512, 0, stream>>>(Xs, W10, W11, G);
    layer12_v2<512, 256><<<6250, 512, 0, stream>>>(G, W20, W21, G);
    layer3_v2<<<6250, 512, 0, stream>>>(G, W30, W31, Xs, WB0, WB1, Gf, stats);
    bn_finalize<<<1, 512, 0, stream>>>(stats, bnw, bnb, params);
    bn_apply<<<4096, 256, 0, stream>>>(Gf, params, out);
}